// Round 4
// baseline (539.618 us; speedup 1.0000x reference)
//
#include <hip/hip_runtime.h>
#include <hip/hip_fp16.h>

// Fixed problem shape
#define TOK   64
#define INF   4096
#define OUTF  11008
#define NUMEL (OUTF * INF)        // 45088768
#define NSLC  (NUMEL / 64)        // 704512 64-element slices
#define NBLK  (OUTF / 16)         // 688 blocks, one per 16-row tile
#define NCH   8                   // K chunks of 512 (full K per block)

// Harness dtypes: fp16 arrays arrive as fp32; ints as int32; output fp32.
typedef __attribute__((ext_vector_type(8))) _Float16 half8;
typedef __attribute__((ext_vector_type(4))) _Float16 half4;
typedef __attribute__((ext_vector_type(4))) float floatx4;
typedef __attribute__((ext_vector_type(4), aligned(4))) int int4u;   // dword-aligned dwordx4
typedef __attribute__((ext_vector_type(4))) int int4a;               // 16B-aligned dwordx4

// LDS B-tile row padding: 512 + 8 fp16 -> row stride 1040 B (16B-aligned,
// dword stride 260 -> even bank spread).
#define BPAD 520

// ---------------------------------------------------------------------------
// Precompute: (a) x fp32 -> fp16 (512 KB, L2-resident GEMM A),
// (b) per-64-slice meta[s] = {c0 = lower_bound(fp16_pos, 64*s),
//     outlier mask lo, mask hi, pad} — one 16 B record.
// ---------------------------------------------------------------------------
__global__ __launch_bounds__(256) void precompute_kernel(
    const float* __restrict__ x, const int* __restrict__ fppos, int nf,
    _Float16* __restrict__ x16, int* __restrict__ meta) {
  const int t = blockIdx.x * 256 + threadIdx.x;
  if (t < (TOK * INF) / 4) {
    const floatx4 f = *(const floatx4*)&x[t * 4];
    half4 h;
    h[0] = (_Float16)f[0]; h[1] = (_Float16)f[1];
    h[2] = (_Float16)f[2]; h[3] = (_Float16)f[3];
    *(half4*)&x16[t * 4] = h;
  }
  if (t < NSLC) {
    const int target = t << 6;
    int lo = 0, hi = nf;
    while (lo < hi) {
      const int mid = (lo + hi) >> 1;
      if (fppos[mid] < target) lo = mid + 1; else hi = mid;
    }
    unsigned long long mask = 0ull;
    int j = lo;
    while (j < nf) {                 // mean 0.17 iters; P(>2) ~ 1e-4
      const int d = fppos[j] - target;
      if (d >= 64) break;
      mask |= 1ull << d;
      ++j;
    }
    int4a mv;
    mv[0] = lo;
    mv[1] = (int)(unsigned)(mask & 0xffffffffu);
    mv[2] = (int)(unsigned)(mask >> 32);
    mv[3] = 0;
    *(int4a*)&meta[t * 4] = mv;
  }
}

// ---------------------------------------------------------------------------
// meta_window: from a slice meta record, compute the compacted i8 index i0 of
// position p0 and the 8-bit outlier window m8. (off is a multiple of 8, so
// the window never straddles the 32-bit halves.)
// ---------------------------------------------------------------------------
__device__ __forceinline__ void meta_window(const int p0, const int4a mv,
                                            int& i0, unsigned& m8) {
  const unsigned mlo = (unsigned)mv[1];
  const unsigned mhi = (unsigned)mv[2];
  const int off = p0 & 63;
  m8 = 0xffu & (off < 32 ? (mlo >> off) : (mhi >> (off - 32)));
  const unsigned bl = (off >= 32) ? mlo : (mlo & ((1u << off) - 1u));
  const unsigned bh = (off >= 32) ? (mhi & ((1u << (off - 32)) - 1u)) : 0u;
  i0 = p0 - mv[0] - (__popc(bl) + __popc(bh));
}

// ---------------------------------------------------------------------------
// finish_slot: combine prefetched i8 dwords + rare fp16 outliers -> half8.
// fpdat index of first outlier >= p0 is p0 - i0 (= c0 + count_below).
// Identical numerics to the R2/R3-verified dequant.
// ---------------------------------------------------------------------------
__device__ __forceinline__ half8 finish_slot(
    const unsigned m8, const int i0, const int p0, const float s,
    const int (&l)[8], const int* __restrict__ i8,
    const float* __restrict__ fpdat, const int n8) {
  const int f = (int)m8;
  float ov[8];
#pragma unroll
  for (int e = 0; e < 8; ++e) ov[e] = 0.f;
  if (f) {
    int fi = p0 - i0;  // c0 + (#outliers below p0)
#pragma unroll
    for (int e = 0; e < 8; ++e) {
      if ((f >> e) & 1) { ov[e] = fpdat[fi]; ++fi; }
    }
  }

  half8 oh;
  if (i0 + 8 <= n8) {
    if (f == 0) {
#pragma unroll
      for (int e = 0; e < 8; ++e) oh[e] = (_Float16)((float)l[e] * s);
    } else {
      int q = 0;
#pragma unroll
      for (int e = 0; e < 8; ++e) {
        const int flg = (f >> e) & 1;
        int lv = l[0];
#pragma unroll
        for (int qq = 1; qq < 8; ++qq) lv = (q == qq) ? l[qq] : lv;
        oh[e] = flg ? (_Float16)ov[e] : (_Float16)((float)lv * s);
        q += 1 - flg;
      }
    }
  } else {
    // Array-tail path (last few global slots only): clamped scalar loads.
    int c = 0;
    const int m = n8 - 1;
#pragma unroll
    for (int e = 0; e < 8; ++e) {
      const int flg = (f >> e) & 1;
      int idx = i0 + e - c;
      idx = idx < 0 ? 0 : (idx > m ? m : idx);
      oh[e] = flg ? (_Float16)ov[e] : (_Float16)((float)i8[idx] * s);
      c += flg;
    }
  }
  return oh;
}

// ---------------------------------------------------------------------------
// Fused GEMM v4 — persistent-K pipelined blocks.
// R1-R3 post-mortem: all variants pinned at ~1.1 TB/s / MfmaUtil 2% /
// VALU 21% regardless of chain depth or atomics -> phase structure limits
// HBM duty cycle (loads in flight only ~15% of wave lifetime; barriers
// gate on slowest load). v4: 688 blocks, FULL K=4096 per block in 8 chunks
// of 512, double-buffered LDS. Per chunk: issue i8(c+1) (meta pre-arrived)
// -> issue meta(c+2) -> MFMA chunk c (loads in flight underneath) ->
// finish dequant(c+1) -> ds_write -> ONE barrier. Accumulators persist
// across K: no K-split, no partials, no reduce kernel, no memset; blocks
// store out+bias directly. c-loop fully unrolled -> all reg-bank indices
// static (no scratch).
// mfma_f32_16x16x32_f16 mapping verified R1-R3 (absmax 0.03125 pass).
// ---------------------------------------------------------------------------
__global__ __launch_bounds__(256) void gemm_fused(
    const _Float16* __restrict__ x16, const int* __restrict__ i8,
    const float* __restrict__ fpdat, const float* __restrict__ scales,
    const int* __restrict__ meta, const float* __restrict__ bias,
    float* __restrict__ out, const int n8) {
  __shared__ __attribute__((aligned(16))) char smem[2 * 16 * BPAD * 2];  // 33.3 KB
  _Float16 (* __restrict__ Bt)[16][BPAD] = (_Float16 (*)[16][BPAD])smem;
  float* red = (float*)smem;  // 16 KB, aliases Bt[0]; used after final phase

  const int tid  = threadIdx.x;
  const int wave = tid >> 6;
  const int lane = tid & 63;
  const int quad = lane >> 4;
  const int ln   = lane & 15;
  const int n0   = blockIdx.x << 4;

  // Slot geometry (constant across chunks): thread's 4 slots cover the
  // 16x512 chunk linearly -> wave = one row's 64 consecutive 8-slots
  // -> i8 reads coalesced (2 KB/wave/slot-group).
  int rL[4], k8o[4];
#pragma unroll
  for (int i = 0; i < 4; ++i) {
    const int slot = i * 256 + tid;
    rL[i]  = slot >> 6;         // local row 0..15
    k8o[i] = (slot & 63) * 8;   // K byte-slot within chunk
  }

  int4a  mreg[2][4];   // meta banks: chunk c lives in bank c&1
  float  sreg[2][4];
  int    lreg[4][8];   // prefetched i8 dwords for chunk c+1
  int    i0v[4];
  unsigned m8v[4];

  // ---- Prologue: meta(0) + meta(1) in flight together ----
#pragma unroll
  for (int i = 0; i < 4; ++i) {
    const int p0 = (n0 + rL[i]) * INF + k8o[i];
    mreg[0][i] = *(const int4a*)&meta[(p0 >> 6) * 4];
    sreg[0][i] = scales[p0 >> 10];
  }
#pragma unroll
  for (int i = 0; i < 4; ++i) {
    const int p0 = (n0 + rL[i]) * INF + 512 + k8o[i];
    mreg[1][i] = *(const int4a*)&meta[(p0 >> 6) * 4];
    sreg[1][i] = scales[p0 >> 10];
  }
  // issue i8(0), finish, stage chunk 0
#pragma unroll
  for (int i = 0; i < 4; ++i) {
    const int p0 = (n0 + rL[i]) * INF + k8o[i];
    meta_window(p0, mreg[0][i], i0v[i], m8v[i]);
    if (i0v[i] + 8 <= n8) {
      *(int4u*)&lreg[i][0] = *(const int4u*)&i8[i0v[i]];
      *(int4u*)&lreg[i][4] = *(const int4u*)&i8[i0v[i] + 4];
    }
  }
#pragma unroll
  for (int i = 0; i < 4; ++i) {
    const int p0 = (n0 + rL[i]) * INF + k8o[i];
    const half8 oh = finish_slot(m8v[i], i0v[i], p0, sreg[0][i], lreg[i],
                                 i8, fpdat, n8);
    *(half8*)&Bt[0][rL[i]][k8o[i]] = oh;
  }
  __syncthreads();

  floatx4 acc0 = {0,0,0,0}, acc1 = {0,0,0,0}, acc2 = {0,0,0,0}, acc3 = {0,0,0,0};

#pragma unroll
  for (int c = 0; c < NCH; ++c) {
    const int cur = c & 1;

    // ---- Issue phase: i8 for c+1 (meta already resident), meta for c+2 ----
    if (c + 1 < NCH) {
      const int bk = (c + 1) & 1;
#pragma unroll
      for (int i = 0; i < 4; ++i) {
        const int p0 = (n0 + rL[i]) * INF + (c + 1) * 512 + k8o[i];
        meta_window(p0, mreg[bk][i], i0v[i], m8v[i]);
        if (i0v[i] + 8 <= n8) {
          *(int4u*)&lreg[i][0] = *(const int4u*)&i8[i0v[i]];
          *(int4u*)&lreg[i][4] = *(const int4u*)&i8[i0v[i] + 4];
        }
      }
      if (c + 2 < NCH) {
        const int bk2 = c & 1;  // bank of meta(c) — consumed last iter, free
#pragma unroll
        for (int i = 0; i < 4; ++i) {
          const int p0 = (n0 + rL[i]) * INF + (c + 2) * 512 + k8o[i];
          mreg[bk2][i] = *(const int4a*)&meta[(p0 >> 6) * 4];
          sreg[bk2][i] = scales[p0 >> 10];
        }
      }
    }

    // ---- MFMA chunk c from LDS (i8/meta loads in flight underneath) ----
    {
      const _Float16* ap = &x16[ln * INF + c * 512 + wave * 128 + quad * 8];
      const _Float16* bp = &Bt[cur][ln][wave * 128 + quad * 8];
#pragma unroll
      for (int st = 0; st < 4; ++st) {
        const int ko = st * 32;
        const half8 bh = *(const half8*)&bp[ko];          // ds_read_b128
        const half8 a0 = *(const half8*)&ap[ko];
        const half8 a1 = *(const half8*)&ap[16 * INF + ko];
        const half8 a2 = *(const half8*)&ap[32 * INF + ko];
        const half8 a3 = *(const half8*)&ap[48 * INF + ko];
        acc0 = __builtin_amdgcn_mfma_f32_16x16x32_f16(a0, bh, acc0, 0, 0, 0);
        acc1 = __builtin_amdgcn_mfma_f32_16x16x32_f16(a1, bh, acc1, 0, 0, 0);
        acc2 = __builtin_amdgcn_mfma_f32_16x16x32_f16(a2, bh, acc2, 0, 0, 0);
        acc3 = __builtin_amdgcn_mfma_f32_16x16x32_f16(a3, bh, acc3, 0, 0, 0);
      }
    }

    // ---- Finish dequant(c+1), write other LDS buffer, one barrier ----
    if (c + 1 < NCH) {
      const int bk = (c + 1) & 1;
      half8 oh[4];
#pragma unroll
      for (int i = 0; i < 4; ++i) {
        const int p0 = (n0 + rL[i]) * INF + (c + 1) * 512 + k8o[i];
        oh[i] = finish_slot(m8v[i], i0v[i], p0, sreg[bk][i], lreg[i],
                            i8, fpdat, n8);
      }
      // Bt[bk] was last read in iter c-1, whose reads completed before that
      // iter's barrier (all waves passed it) -> writes are safe now.
#pragma unroll
      for (int i = 0; i < 4; ++i)
        *(half8*)&Bt[bk][rL[i]][k8o[i]] = oh[i];
      __syncthreads();
    }
  }

  // ---- Cross-wave reduce (red aliases Bt[0]; Bt[0] last read in chunk 6,
  // ordered by chunk 6's barrier; concurrent Bt[1] reads are disjoint) ----
  const int mb = quad * 4;
#pragma unroll
  for (int i = 0; i < 4; ++i) red[wave * 1024 + (mb + i)      * 16 + ln] = acc0[i];
#pragma unroll
  for (int i = 0; i < 4; ++i) red[wave * 1024 + (16 + mb + i) * 16 + ln] = acc1[i];
#pragma unroll
  for (int i = 0; i < 4; ++i) red[wave * 1024 + (32 + mb + i) * 16 + ln] = acc2[i];
#pragma unroll
  for (int i = 0; i < 4; ++i) red[wave * 1024 + (48 + mb + i) * 16 + ln] = acc3[i];
  __syncthreads();

#pragma unroll
  for (int c2 = 0; c2 < 4; ++c2) {
    const int cell = tid + c2 * 256;  // 1024 cells = 64 m x 16 n
    const int mm = cell >> 4, nn = cell & 15;
    const float v = red[cell] + red[1024 + cell] + red[2048 + cell]
                  + red[3072 + cell] + bias[n0 + nn];
    out[mm * OUTF + n0 + nn] = v;
  }
}

// ---------------------------------------------------------------------------
// Inputs: 0 x(fp32) 1 int8_data(i32) 2 fp16_data(fp32) 3 scales(fp32)
// 4 bias(fp32) 5 int8_pos(UNUSED) 6 fp16_pos(i32) 7 block_idx(UNUSED)
// ws: x16 (512 KB) | meta (11.3 MB)     — part/reduce/memset all removed
// ---------------------------------------------------------------------------
extern "C" void kernel_launch(void* const* d_in, const int* in_sizes, int n_in,
                              void* d_out, int out_size, void* d_ws,
                              size_t ws_size, hipStream_t stream) {
  const float* x      = (const float*)d_in[0];
  const int*   i8     = (const int*)d_in[1];
  const float* fpdat  = (const float*)d_in[2];
  const float* scales = (const float*)d_in[3];
  const float* bias   = (const float*)d_in[4];
  const int*   fppos  = (const int*)d_in[6];

  char* wsp = (char*)d_ws;
  _Float16* x16  = (_Float16*)wsp;
  int*      meta = (int*)(wsp + (size_t)TOK * INF * sizeof(_Float16));
  float*    out  = (float*)d_out;

  const int n8 = in_sizes[1];
  const int nf = in_sizes[2];

  precompute_kernel<<<NSLC / 256, 256, 0, stream>>>(x, fppos, nf, x16, meta);
  gemm_fused<<<NBLK, 256, 0, stream>>>(x16, i8, fpdat, scales, meta, bias,
                                       out, n8);
}

// Round 5
// 460.505 us; speedup vs baseline: 1.1718x; 1.1718x over previous
//
#include <hip/hip_runtime.h>
#include <hip/hip_fp16.h>

// Fixed problem shape
#define TOK   64
#define INF   4096
#define OUTF  11008
#define NUMEL (OUTF * INF)        // 45088768
#define NSLC  (NUMEL / 64)        // 704512 64-element slices
#define NBLK  (OUTF / 16)         // 688 N-tiles
#define KSPL  4                   // K-split -> 2752 blocks, K=1024 each
#define NCH   4                   // chunks of 256 K per block
#define OUTN  (TOK * OUTF)        // 704512 output elems

// Harness dtypes: fp16 arrays arrive as fp32; ints as int32; output fp32.
typedef __attribute__((ext_vector_type(8))) _Float16 half8;
typedef __attribute__((ext_vector_type(4))) _Float16 half4;
typedef __attribute__((ext_vector_type(4))) float floatx4;
typedef __attribute__((ext_vector_type(4), aligned(4))) int int4u;   // dword-aligned dwordx4
typedef __attribute__((ext_vector_type(4))) int int4a;               // 16B-aligned dwordx4

// LDS B-tile row: 256 + 8 fp16 -> stride 528 B (16B-aligned; dword stride
// 132 -> rows advance 4 banks, even spread).
#define BPAD 264

// ---------------------------------------------------------------------------
// Precompute: (a) x fp32 -> fp16 (512 KB, L2-resident GEMM A),
// (b) per-64-slice meta[s] = {c0 = lower_bound(fp16_pos, 64*s),
//     outlier mask lo, mask hi, pad} — one 16 B record.
// ---------------------------------------------------------------------------
__global__ __launch_bounds__(256) void precompute_kernel(
    const float* __restrict__ x, const int* __restrict__ fppos, int nf,
    _Float16* __restrict__ x16, int* __restrict__ meta) {
  const int t = blockIdx.x * 256 + threadIdx.x;
  if (t < (TOK * INF) / 4) {
    const floatx4 f = *(const floatx4*)&x[t * 4];
    half4 h;
    h[0] = (_Float16)f[0]; h[1] = (_Float16)f[1];
    h[2] = (_Float16)f[2]; h[3] = (_Float16)f[3];
    *(half4*)&x16[t * 4] = h;
  }
  if (t < NSLC) {
    const int target = t << 6;
    int lo = 0, hi = nf;
    while (lo < hi) {
      const int mid = (lo + hi) >> 1;
      if (fppos[mid] < target) lo = mid + 1; else hi = mid;
    }
    unsigned long long mask = 0ull;
    int j = lo;
    while (j < nf) {                 // mean 0.17 iters; P(>2) ~ 1e-4
      const int d = fppos[j] - target;
      if (d >= 64) break;
      mask |= 1ull << d;
      ++j;
    }
    int4a mv;
    mv[0] = lo;
    mv[1] = (int)(unsigned)(mask & 0xffffffffu);
    mv[2] = (int)(unsigned)(mask >> 32);
    mv[3] = 0;
    *(int4a*)&meta[t * 4] = mv;
  }
}

// ---------------------------------------------------------------------------
// meta_window: compacted i8 index i0 of position p0 + 8-bit outlier window.
// (off is a multiple of 8, so the window never straddles the 32-bit halves.)
// ---------------------------------------------------------------------------
__device__ __forceinline__ void meta_window(const int p0, const int4a mv,
                                            int& i0, unsigned& m8) {
  const unsigned mlo = (unsigned)mv[1];
  const unsigned mhi = (unsigned)mv[2];
  const int off = p0 & 63;
  m8 = 0xffu & (off < 32 ? (mlo >> off) : (mhi >> (off - 32)));
  const unsigned bl = (off >= 32) ? mlo : (mlo & ((1u << off) - 1u));
  const unsigned bh = (off >= 32) ? (mhi & ((1u << (off - 32)) - 1u)) : 0u;
  i0 = p0 - mv[0] - (__popc(bl) + __popc(bh));
}

// ---------------------------------------------------------------------------
// finish_slot: combine prefetched i8 dwords + rare fp16 outliers -> half8.
// Identical numerics to the R2-R4-verified dequant.
// ---------------------------------------------------------------------------
__device__ __forceinline__ half8 finish_slot(
    const unsigned m8, const int i0, const int p0, const float s,
    const int (&l)[8], const int* __restrict__ i8,
    const float* __restrict__ fpdat, const int n8) {
  const int f = (int)m8;
  float ov[8];
#pragma unroll
  for (int e = 0; e < 8; ++e) ov[e] = 0.f;
  if (f) {
    int fi = p0 - i0;  // c0 + (#outliers below p0)
#pragma unroll
    for (int e = 0; e < 8; ++e) {
      if ((f >> e) & 1) { ov[e] = fpdat[fi]; ++fi; }
    }
  }

  half8 oh;
  if (i0 + 8 <= n8) {
    if (f == 0) {
#pragma unroll
      for (int e = 0; e < 8; ++e) oh[e] = (_Float16)((float)l[e] * s);
    } else {
      int q = 0;
#pragma unroll
      for (int e = 0; e < 8; ++e) {
        const int flg = (f >> e) & 1;
        int lv = l[0];
#pragma unroll
        for (int qq = 1; qq < 8; ++qq) lv = (q == qq) ? l[qq] : lv;
        oh[e] = flg ? (_Float16)ov[e] : (_Float16)((float)lv * s);
        q += 1 - flg;
      }
    }
  } else {
    // Array-tail path (last few global slots only): clamped scalar loads.
    int c = 0;
    const int m = n8 - 1;
#pragma unroll
    for (int e = 0; e < 8; ++e) {
      const int flg = (f >> e) & 1;
      int idx = i0 + e - c;
      idx = idx < 0 ? 0 : (idx > m ? m : idx);
      oh[e] = flg ? (_Float16)ov[e] : (_Float16)((float)i8[idx] * s);
      c += flg;
    }
  }
  return oh;
}

// ---------------------------------------------------------------------------
// Fused GEMM v5 — R4's pipeline at R3's grid.
// R4 post-mortem: per-chunk throughput 4x better than R3 (7.6 vs 31 us per
// 16x512) but grid of 688 blocks starved the device (occ 10%). v5: KSPL=4
// -> 2752 blocks (R1-proven residency), K=1024/block as 4 chunks of 256,
// 2 slots/thread (halved persistent regs; __launch_bounds__(256,4) caps
// VGPR at 128 -> 4 blocks/CU). Per chunk: issue i8(c+1) (meta pre-arrived)
// -> issue meta(c+2) -> MFMA(c) (loads in flight underneath) -> finish(c+1)
// -> ds_write -> ONE barrier. Partials + tiny reduce (no atomics/memset).
// mfma_f32_16x16x32_f16 mapping verified R1-R4 (absmax 0.03125 pass).
// ---------------------------------------------------------------------------
__global__ __launch_bounds__(256, 4) void gemm_fused(
    const _Float16* __restrict__ x16, const int* __restrict__ i8,
    const float* __restrict__ fpdat, const float* __restrict__ scales,
    const int* __restrict__ meta, float* __restrict__ part, const int n8) {
  __shared__ __attribute__((aligned(16))) char smem[2 * 16 * BPAD * 2];  // 16.9 KB
  _Float16 (* __restrict__ Bt)[16][BPAD] = (_Float16 (*)[16][BPAD])smem;
  float* red = (float*)smem;  // 16 KB, aliases both Bt buffers; used at end

  const int tid  = threadIdx.x;
  const int wave = tid >> 6;
  const int lane = tid & 63;
  const int quad = lane >> 4;
  const int ln   = lane & 15;
  const int nt   = blockIdx.x >> 2;
  const int kq   = blockIdx.x & 3;
  const int n0   = nt << 4;
  const int kbas = kq * 1024;

  // Slot geometry (constant across chunks): 512 slots cover the 16x256
  // chunk linearly; a wave's 64 consecutive slots = 2 rows x 1 KB of i8
  // each -> coalesced.
  int rL[2], k8o[2];
#pragma unroll
  for (int i = 0; i < 2; ++i) {
    const int slot = i * 256 + tid;
    rL[i]  = slot >> 5;         // local row 0..15 (32 slots/row)
    k8o[i] = (slot & 31) * 8;   // K offset within chunk
  }

  int4a    mreg[2][2];   // meta banks: chunk c lives in bank c&1
  float    sreg[2][2];
  int      lreg[2][8];   // prefetched i8 dwords for chunk c+1
  int      i0v[2];
  unsigned m8v[2];

  // ---- Prologue: meta(0)+meta(1) in flight; then i8(0); stage chunk 0 ----
#pragma unroll
  for (int i = 0; i < 2; ++i) {
    const int p0 = (n0 + rL[i]) * INF + kbas + k8o[i];
    mreg[0][i] = *(const int4a*)&meta[(p0 >> 6) * 4];
    sreg[0][i] = scales[p0 >> 10];
  }
#pragma unroll
  for (int i = 0; i < 2; ++i) {
    const int p0 = (n0 + rL[i]) * INF + kbas + 256 + k8o[i];
    mreg[1][i] = *(const int4a*)&meta[(p0 >> 6) * 4];
    sreg[1][i] = scales[p0 >> 10];
  }
#pragma unroll
  for (int i = 0; i < 2; ++i) {
    const int p0 = (n0 + rL[i]) * INF + kbas + k8o[i];
    meta_window(p0, mreg[0][i], i0v[i], m8v[i]);
    if (i0v[i] + 8 <= n8) {
      *(int4u*)&lreg[i][0] = *(const int4u*)&i8[i0v[i]];
      *(int4u*)&lreg[i][4] = *(const int4u*)&i8[i0v[i] + 4];
    }
  }
#pragma unroll
  for (int i = 0; i < 2; ++i) {
    const int p0 = (n0 + rL[i]) * INF + kbas + k8o[i];
    const half8 oh = finish_slot(m8v[i], i0v[i], p0, sreg[0][i], lreg[i],
                                 i8, fpdat, n8);
    *(half8*)&Bt[0][rL[i]][k8o[i]] = oh;
  }
  __syncthreads();

  floatx4 acc0 = {0,0,0,0}, acc1 = {0,0,0,0}, acc2 = {0,0,0,0}, acc3 = {0,0,0,0};

#pragma unroll
  for (int c = 0; c < NCH; ++c) {
    const int cur = c & 1;

    // ---- Issue: i8 for c+1 (meta resident), meta for c+2 ----
    if (c + 1 < NCH) {
      const int bk = (c + 1) & 1;
#pragma unroll
      for (int i = 0; i < 2; ++i) {
        const int p0 = (n0 + rL[i]) * INF + kbas + (c + 1) * 256 + k8o[i];
        meta_window(p0, mreg[bk][i], i0v[i], m8v[i]);
        if (i0v[i] + 8 <= n8) {
          *(int4u*)&lreg[i][0] = *(const int4u*)&i8[i0v[i]];
          *(int4u*)&lreg[i][4] = *(const int4u*)&i8[i0v[i] + 4];
        }
      }
      if (c + 2 < NCH) {
        const int bk2 = c & 1;  // bank of meta(c) — consumed, free
#pragma unroll
        for (int i = 0; i < 2; ++i) {
          const int p0 = (n0 + rL[i]) * INF + kbas + (c + 2) * 256 + k8o[i];
          mreg[bk2][i] = *(const int4a*)&meta[(p0 >> 6) * 4];
          sreg[bk2][i] = scales[p0 >> 10];
        }
      }
    }

    // ---- MFMA chunk c from LDS (i8/meta loads in flight underneath) ----
    // wave = 64-K slice of the 256 chunk, 2 steps of 32; 4 M-tiles.
    {
      const _Float16* ap = &x16[ln * INF + kbas + c * 256 + wave * 64 + quad * 8];
      const _Float16* bp = &Bt[cur][ln][wave * 64 + quad * 8];
#pragma unroll
      for (int st = 0; st < 2; ++st) {
        const int ko = st * 32;
        const half8 bh = *(const half8*)&bp[ko];          // ds_read_b128
        const half8 a0 = *(const half8*)&ap[ko];
        const half8 a1 = *(const half8*)&ap[16 * INF + ko];
        const half8 a2 = *(const half8*)&ap[32 * INF + ko];
        const half8 a3 = *(const half8*)&ap[48 * INF + ko];
        acc0 = __builtin_amdgcn_mfma_f32_16x16x32_f16(a0, bh, acc0, 0, 0, 0);
        acc1 = __builtin_amdgcn_mfma_f32_16x16x32_f16(a1, bh, acc1, 0, 0, 0);
        acc2 = __builtin_amdgcn_mfma_f32_16x16x32_f16(a2, bh, acc2, 0, 0, 0);
        acc3 = __builtin_amdgcn_mfma_f32_16x16x32_f16(a3, bh, acc3, 0, 0, 0);
      }
    }

    // ---- Finish dequant(c+1), write other LDS buffer, one barrier ----
    if (c + 1 < NCH) {
      const int bk = (c + 1) & 1;
      half8 oh[2];
#pragma unroll
      for (int i = 0; i < 2; ++i) {
        const int p0 = (n0 + rL[i]) * INF + kbas + (c + 1) * 256 + k8o[i];
        oh[i] = finish_slot(m8v[i], i0v[i], p0, sreg[bk][i], lreg[i],
                            i8, fpdat, n8);
      }
      // Bt[bk] last read in iter c-1; those reads precede barrier(c-1),
      // which all waves have passed -> writes safe.
#pragma unroll
      for (int i = 0; i < 2; ++i)
        *(half8*)&Bt[bk][rL[i]][k8o[i]] = oh[i];
      __syncthreads();
    }
  }
  // red (16 KB) spans BOTH Bt buffers; last chunk's MFMA reads Bt[1] ->
  // barrier before the alias writes.
  __syncthreads();

  // ---- Cross-wave reduce ----
  const int mb = quad * 4;
#pragma unroll
  for (int i = 0; i < 4; ++i) red[wave * 1024 + (mb + i)      * 16 + ln] = acc0[i];
#pragma unroll
  for (int i = 0; i < 4; ++i) red[wave * 1024 + (16 + mb + i) * 16 + ln] = acc1[i];
#pragma unroll
  for (int i = 0; i < 4; ++i) red[wave * 1024 + (32 + mb + i) * 16 + ln] = acc2[i];
#pragma unroll
  for (int i = 0; i < 4; ++i) red[wave * 1024 + (48 + mb + i) * 16 + ln] = acc3[i];
  __syncthreads();

  // ---- Plain partial store ----
  float* pp = &part[(size_t)kq * OUTN];
#pragma unroll
  for (int c2 = 0; c2 < 4; ++c2) {
    const int cell = tid + c2 * 256;  // 1024 cells = 64 m x 16 n
    const int mm = cell >> 4, nn = cell & 15;
    pp[mm * OUTF + n0 + nn] =
        red[cell] + red[1024 + cell] + red[2048 + cell] + red[3072 + cell];
  }
}

// ---------------------------------------------------------------------------
// Reduce: out = sum_kq part[kq] + bias. 11.3 MB read + 2.8 MB write ~ 3 us.
// ---------------------------------------------------------------------------
__global__ __launch_bounds__(256) void reduce_kernel(
    const float* __restrict__ part, const float* __restrict__ bias,
    float* __restrict__ out) {
  const int t  = blockIdx.x * 256 + threadIdx.x;  // 688*256 = 176128 exact
  const int i4 = t * 4;
  floatx4 a = *(const floatx4*)&part[i4];
#pragma unroll
  for (int k = 1; k < KSPL; ++k) {
    const floatx4 b = *(const floatx4*)&part[(size_t)k * OUTN + i4];
    a[0] += b[0]; a[1] += b[1]; a[2] += b[2]; a[3] += b[3];
  }
  const int nn = i4 % OUTF;  // OUTF % 4 == 0: float4 never straddles rows
  const floatx4 bb = *(const floatx4*)&bias[nn];
  a[0] += bb[0]; a[1] += bb[1]; a[2] += bb[2]; a[3] += bb[3];
  *(floatx4*)&out[i4] = a;
}

// ---------------------------------------------------------------------------
// Inputs: 0 x(fp32) 1 int8_data(i32) 2 fp16_data(fp32) 3 scales(fp32)
// 4 bias(fp32) 5 int8_pos(UNUSED) 6 fp16_pos(i32) 7 block_idx(UNUSED)
// ws: x16 (512 KB) | meta (11.3 MB) | part (11.3 MB)
// ---------------------------------------------------------------------------
extern "C" void kernel_launch(void* const* d_in, const int* in_sizes, int n_in,
                              void* d_out, int out_size, void* d_ws,
                              size_t ws_size, hipStream_t stream) {
  const float* x      = (const float*)d_in[0];
  const int*   i8     = (const int*)d_in[1];
  const float* fpdat  = (const float*)d_in[2];
  const float* scales = (const float*)d_in[3];
  const float* bias   = (const float*)d_in[4];
  const int*   fppos  = (const int*)d_in[6];

  char* wsp = (char*)d_ws;
  _Float16* x16  = (_Float16*)wsp;
  int*      meta = (int*)(wsp + (size_t)TOK * INF * sizeof(_Float16));
  float*    part = (float*)(wsp + (size_t)TOK * INF * sizeof(_Float16)
                                + (size_t)NSLC * 16);
  float*    out  = (float*)d_out;

  const int n8 = in_sizes[1];
  const int nf = in_sizes[2];

  precompute_kernel<<<NSLC / 256, 256, 0, stream>>>(x, fppos, nf, x16, meta);
  gemm_fused<<<NBLK * KSPL, 256, 0, stream>>>(x16, i8, fpdat, scales, meta,
                                              part, n8);
  reduce_kernel<<<OUTN / (4 * 256), 256, 0, stream>>>(part, bias, out);
}